// Round 9
// baseline (347.579 us; speedup 1.0000x reference)
//
#include <hip/hip_runtime.h>

typedef __attribute__((ext_vector_type(4))) float f32x4;
typedef __attribute__((ext_vector_type(4))) int i32x4;
typedef __attribute__((ext_vector_type(16))) int i32x16;
typedef __attribute__((ext_vector_type(8))) __bf16 bf16x8;

__device__ __forceinline__ unsigned short f2bf(float f) {
  union { float f; unsigned u; } v; v.f = f;
  unsigned r = v.u + 0x7fffu + ((v.u >> 16) & 1u);
  return (unsigned short)(r >> 16);
}

__device__ __forceinline__ void gll16(const void* g, void* s) {
  __builtin_amdgcn_global_load_lds((const __attribute__((address_space(1))) unsigned int*)g,
                                   (__attribute__((address_space(3))) unsigned int*)s, 16, 0, 0);
}

__device__ __forceinline__ int quant8(float x, float s) {
  return (int)rintf(fminf(fmaxf(x * s, -127.f), 127.f));
}

#define MFMA(a, b, c) __builtin_amdgcn_mfma_f32_16x16x32_bf16((a), (b), (c), 0, 0, 0)
#define MFMA_I8_32(a, b, c) __builtin_amdgcn_mfma_i32_32x32x32_i8((a), (b), (c), 0, 0, 0)

// Counted-vmcnt pipeline barriers (T4): wait only for the stage issued one
// iteration ago (N = VMEM ops/thread/stage in flight), never drain mid-loop.
template <int N>
__device__ __forceinline__ void pipe_wait() {
  if constexpr (N == 8) asm volatile("s_waitcnt vmcnt(8)" ::: "memory");
  else if constexpr (N == 4) asm volatile("s_waitcnt vmcnt(4)" ::: "memory");
  else asm volatile("s_waitcnt vmcnt(0)" ::: "memory");
  __builtin_amdgcn_s_barrier();
  __builtin_amdgcn_sched_barrier(0);
}
__device__ __forceinline__ void pipe_post() {
  __builtin_amdgcn_s_barrier();
  __builtin_amdgcn_sched_barrier(0);
}

// Generic LDS block swizzle for RB-byte rows (RB in {64,128}); 16B blocks.
// RB=128 -> full XOR over row&7; RB=64 -> (row>>1)&3, 2-way aliasing (free, m136).
template <int RB>
__device__ __forceinline__ int swz(int row) {
  return ((row * RB) >> 7) & (RB / 16 - 1);
}

// ---------------- fp32 -> bf16 convert (x, w_qkv, w_out) ----------------
__global__ __launch_bounds__(256) void convert_kernel(
    const float* __restrict__ x, const float* __restrict__ wqkv, const float* __restrict__ wout,
    unsigned short* __restrict__ xb, unsigned short* __restrict__ wqkvb,
    unsigned short* __restrict__ woutb) {
  const long i4 = (long)blockIdx.x * 256 + threadIdx.x;
  const float4* src;
  unsigned short* dst;
  long j;
  if (i4 < 2097152) { src = (const float4*)x; j = i4; dst = xb; }
  else if (i4 < 2883584) { src = (const float4*)wqkv; j = i4 - 2097152; dst = wqkvb; }
  else { src = (const float4*)wout; j = i4 - 2883584; dst = woutb; }
  const float4 v = src[j];
  ushort4 r;
  r.x = f2bf(v.x); r.y = f2bf(v.y); r.z = f2bf(v.z); r.w = f2bf(v.w);
  *(ushort4*)(dst + j * 4) = r;
}

// ---- bf16 128x128 GEMM mainloop, depth-2 counted-vmcnt (R2-proven; no setprio) ----
template <int RB>
__device__ __forceinline__ void gemm_tile2(const unsigned short* __restrict__ A, int lda,
                                           const unsigned short* __restrict__ B, int ldb,
                                           int nstages,  // even, >= 4
                                           unsigned short* As0, unsigned short* As1,
                                           unsigned short* Bs0, unsigned short* Bs1,
                                           f32x4 acc[4][4]) {
  constexpr int SLOTS = RB / 16;   // 16B slots per row
  constexpr int RPC = 1024 / RB;   // rows per 1KB chunk
  constexpr int CPW = RB / 32;     // chunks per wave per operand
  constexpr int WAIT = RB / 16;    // loads/thread/stage (A+B)
  const int tid = threadIdx.x;
  const int w = tid >> 6, l = tid & 63, lane15 = l & 15, quad = l >> 4;
#pragma unroll
  for (int br = 0; br < 4; ++br)
#pragma unroll
    for (int bc = 0; bc < 4; ++bc) acc[br][bc] = f32x4{0.f, 0.f, 0.f, 0.f};
  const int ar0 = 64 * (w >> 1), bc0 = 64 * (w & 1);

  auto stage = [&](unsigned short* as, unsigned short* bs, int st) {
    const int kc = st * (RB / 2);
#pragma unroll
    for (int t = 0; t < CPW; ++t) {
      const int ck = w * CPW + t;
      const int row = ck * RPC + l / SLOTS;
      const int x = (l & (SLOTS - 1)) ^ swz<RB>(row);
      gll16(A + (size_t)row * lda + kc + x * 8, as + ck * 512);
      gll16(B + (size_t)row * ldb + kc + x * 8, bs + ck * 512);
    }
  };
  auto comp = [&](const unsigned short* as, const unsigned short* bs) {
#pragma unroll
    for (int kk = 0; kk < RB / 64; ++kk) {
      bf16x8 a[4], b[4];
#pragma unroll
      for (int br = 0; br < 4; ++br) {
        const int row = ar0 + 16 * br + lane15;
        const int blk = (kk * 4 + quad) ^ swz<RB>(row);
        a[br] = *(const bf16x8*)((const char*)as + row * RB + blk * 16);
      }
#pragma unroll
      for (int bc = 0; bc < 4; ++bc) {
        const int row = bc0 + 16 * bc + lane15;
        const int blk = (kk * 4 + quad) ^ swz<RB>(row);
        b[bc] = *(const bf16x8*)((const char*)bs + row * RB + blk * 16);
      }
#pragma unroll
      for (int br = 0; br < 4; ++br)
#pragma unroll
        for (int bc = 0; bc < 4; ++bc)
          acc[br][bc] = MFMA(a[br], b[bc], acc[br][bc]);
    }
  };

  stage(As0, Bs0, 0);
  stage(As1, Bs1, 1);
  for (int st = 0; st < nstages - 2; st += 2) {
    pipe_wait<WAIT>();
    comp(As0, Bs0);
    pipe_post();
    stage(As0, Bs0, st + 2);
    pipe_wait<WAIT>();
    comp(As1, Bs1);
    pipe_post();
    stage(As1, Bs1, st + 3);
  }
  pipe_wait<WAIT>();
  comp(As0, Bs0);
  pipe_wait<0>();
  comp(As1, Bs1);
  __syncthreads();  // epilogues may reuse LDS
}

// ---- i8 128x128 GEMM mainloop on mfma_i32_32x32x32_i8 (2x ops per LDS byte
// and per MFMA issue vs 16x16x64). 2-buffer depth-2 counted-vmcnt (R2-proven
// pipeline). Per wave: 64x64 output = 2x2 tiles of 32x32 (i32x16 acc each).
// A-frag: row = l&31 (+32*tr), k = 16*(l>>5) + 0..15 contiguous (same contiguous
// per-lane-K pattern proven by the working 16x16x64 loop). C/D: col = lane&31,
// row = (reg&3) + 8*(reg>>2) + 4*(lane>>5)  [HW-verified m74/m101].
// SUM: exact row-sums of A via ones-column MFMA. PRIO: setprio around MFMA. ----
template <bool SUM, int RB, bool PRIO>
__device__ __forceinline__ void gemm_i8_32(const unsigned char* __restrict__ A, int lda,
                                           const unsigned char* __restrict__ B, int ldb,
                                           int nstages,  // even, >= 4
                                           unsigned char* As0, unsigned char* As1,
                                           unsigned char* Bs0, unsigned char* Bs1,
                                           i32x16 acc[2][2], i32x16* accs) {
  constexpr int SLOTS = RB / 16;
  constexpr int RPC = 1024 / RB;
  constexpr int CPW = RB / 32;  // staging chunks per wave per operand
  constexpr int WAIT = RB / 16;
  const int tid = threadIdx.x;
  const int w = tid >> 6, l = tid & 63, l31 = l & 31, half = l >> 5;
#pragma unroll
  for (int tr = 0; tr < 2; ++tr)
#pragma unroll
    for (int tc = 0; tc < 2; ++tc)
#pragma unroll
      for (int r = 0; r < 16; ++r) acc[tr][tc][r] = 0;
  if constexpr (SUM) {
#pragma unroll
    for (int tr = 0; tr < 2; ++tr)
#pragma unroll
      for (int r = 0; r < 16; ++r) accs[tr][r] = 0;
  }
  const int ar0 = 64 * (w >> 1), bc0 = 64 * (w & 1);

  auto stage = [&](unsigned char* as, unsigned char* bs, int st) {
    const int kc = st * RB;
#pragma unroll
    for (int t = 0; t < CPW; ++t) {
      const int ck = w * CPW + t;
      const int row = ck * RPC + l / SLOTS;
      const int x = (l & (SLOTS - 1)) ^ swz<RB>(row);
      gll16(A + (size_t)row * lda + kc + x * 16, as + ck * 1024);
      gll16(B + (size_t)row * ldb + kc + x * 16, bs + ck * 1024);
    }
  };
  auto comp = [&](const unsigned char* as, const unsigned char* bs) {
#pragma unroll
    for (int kk = 0; kk < RB / 32; ++kk) {  // K-steps of 32 bytes
      i32x4 a[2], b[2];
#pragma unroll
      for (int tr = 0; tr < 2; ++tr) {
        const int row = ar0 + 32 * tr + l31;
        const int blk = (kk * 2 + half) ^ swz<RB>(row);
        a[tr] = *(const i32x4*)(as + row * RB + blk * 16);
      }
#pragma unroll
      for (int tc = 0; tc < 2; ++tc) {
        const int row = bc0 + 32 * tc + l31;
        const int blk = (kk * 2 + half) ^ swz<RB>(row);
        b[tc] = *(const i32x4*)(bs + row * RB + blk * 16);
      }
      if constexpr (PRIO) __builtin_amdgcn_s_setprio(1);
      if constexpr (SUM) {
        const i32x4 ones = {0x01010101, 0x01010101, 0x01010101, 0x01010101};
#pragma unroll
        for (int tr = 0; tr < 2; ++tr) accs[tr] = MFMA_I8_32(a[tr], ones, accs[tr]);
      }
#pragma unroll
      for (int tr = 0; tr < 2; ++tr)
#pragma unroll
        for (int tc = 0; tc < 2; ++tc)
          acc[tr][tc] = MFMA_I8_32(a[tr], b[tc], acc[tr][tc]);
      if constexpr (PRIO) __builtin_amdgcn_s_setprio(0);
    }
  };

  stage(As0, Bs0, 0);
  stage(As1, Bs1, 1);
  for (int st = 0; st < nstages - 2; st += 2) {
    pipe_wait<WAIT>();
    comp(As0, Bs0);
    pipe_post();
    stage(As0, Bs0, st + 2);
    pipe_wait<WAIT>();
    comp(As1, Bs1);
    pipe_post();
    stage(As1, Bs1, st + 3);
  }
  pipe_wait<WAIT>();
  comp(As0, Bs0);
  pipe_wait<0>();
  comp(As1, Bs1);
  __syncthreads();  // epilogues may reuse LDS
}

// ---------------- QKV projection (bf16 GEMM) -> Q8/K8 [8192][1024] i8 (x32), V8^T [1024][8192] i8 (x32) ----------------
__global__ __launch_bounds__(256) void qkv_kernel(
    const unsigned short* __restrict__ xb, const unsigned short* __restrict__ wb,
    const float* __restrict__ bias, unsigned char* __restrict__ Q8,
    unsigned char* __restrict__ K8, unsigned char* __restrict__ V8) {
  __shared__ alignas(16) unsigned short As0[8192], As1[8192], Bs0[8192], Bs1[8192];  // 64KB
  const int bx0 = blockIdx.x;
  // XCD-chunked swizzle (1536 % 8 == 0, bijective)
  const int bx = (bx0 & 7) * 192 + (bx0 >> 3);
  const int tn = bx % 24, tm = bx / 24;
  f32x4 acc[4][4];
  gemm_tile2<128>(xb + (size_t)(tm * 128) * 1024, 1024, wb + (size_t)(tn * 128) * 1024, 1024, 16,
                  As0, As1, Bs0, Bs1, acc);
  const int tid = threadIdx.x, w = tid >> 6, l = tid & 63, lane15 = l & 15, quad = l >> 4;
  const int rl0 = 64 * (w >> 1), cl0 = 64 * (w & 1);
  float bq[4];
#pragma unroll
  for (int bc = 0; bc < 4; ++bc) bq[bc] = bias[tn * 128 + cl0 + 16 * bc + lane15];
  if (tn < 16) {  // Q or K tile: quantize to i8, LDS transpose, coalesced 16B stores
    unsigned char* sm8 = (unsigned char*)As0;  // 16KB: full 128x128 i8 tile
#pragma unroll
    for (int br = 0; br < 4; ++br)
#pragma unroll
      for (int bc = 0; bc < 4; ++bc)
#pragma unroll
        for (int i = 0; i < 4; ++i) {
          const int row = rl0 + 16 * br + 4 * quad + i;
          const int col = cl0 + 16 * bc + lane15;
          const int q = quant8(acc[br][bc][i] + bq[bc], 32.f);
          sm8[row * 128 + (((col >> 4) ^ (row & 7)) << 4) + (col & 15)] = (unsigned char)q;
        }
    __syncthreads();
    unsigned char* dst = (tn < 8) ? Q8 : K8;
    const int ccol = (tn < 8) ? tn * 128 : (tn - 8) * 128;
#pragma unroll
    for (int t = 0; t < 4; ++t) {
      const int cid = t * 256 + tid;
      const int row = cid >> 3, blk = cid & 7;
      const i32x4 v = *(const i32x4*)(sm8 + row * 128 + ((blk ^ (row & 7)) << 4));
      *(i32x4*)(dst + (size_t)(tm * 128 + row) * 1024 + ccol + blk * 16) = v;
    }
  } else {  // V tile -> transposed i8 store V8[d][s], 4 consecutive s packed per int
#pragma unroll
    for (int br = 0; br < 4; ++br)
#pragma unroll
      for (int bc = 0; bc < 4; ++bc) {
        int pk = 0;
#pragma unroll
        for (int i = 0; i < 4; ++i) {
          const int q = quant8(acc[br][bc][i] + bq[bc], 32.f);
          pk |= (q & 255) << (8 * i);
        }
        const int d = (tn - 16) * 128 + cl0 + 16 * bc + lane15;
        const int s = tm * 128 + rl0 + 16 * br + 4 * quad;
        *(int*)(V8 + (size_t)d * 8192 + s) = pk;
      }
  }
}

// ---------------- score: P8[8192][8192] = i8(exp(QK^T/32) * 16), natural k-order ----------------
// 32x32 i8 MFMA mainloop; LDS-transpose epilogue (R2-proven) for coalesced stores.
__global__ __launch_bounds__(256) void score8_kernel(
    const unsigned char* __restrict__ Q8, const unsigned char* __restrict__ K8,
    unsigned char* __restrict__ P8) {
  __shared__ alignas(16) unsigned char As0[8192], As1[8192], Bs0[8192], Bs1[8192];  // 32KB
  const int tm = blockIdx.x >> 6, tn = blockIdx.x & 63;
  i32x16 acc[2][2];
  gemm_i8_32<false, 64, true>(Q8 + (size_t)(tm * 128) * 1024, 1024,
                              K8 + (size_t)(tn * 128) * 1024, 1024, 16, As0, As1, Bs0, Bs1, acc,
                              (i32x16*)nullptr);
  const int tid = threadIdx.x, w = tid >> 6, l = tid & 63, l31 = l & 31, half = l >> 5;
  const int cl0 = 64 * (w & 1);
  // quantize -> LDS (rows 0..63 of the tile in As0, 64..127 in As1; rl0 picks)
  unsigned char* sm8 = (w < 2) ? As0 : As1;
  const float csc = 1.0f / 32768.0f;  // 1/(32*32) quant scales * 1/32 softmax scale
#pragma unroll
  for (int tr = 0; tr < 2; ++tr)
#pragma unroll
    for (int tc = 0; tc < 2; ++tc)
#pragma unroll
      for (int r = 0; r < 16; ++r) {
        const int row = 32 * tr + (r & 3) + 8 * (r >> 2) + 4 * half;  // local 0..63
        const int col = cl0 + 32 * tc + l31;
        // p*16 = exp(x)*16 = exp(x + ln16)
        const float p16 = __expf(fmaf((float)acc[tr][tc][r], csc, 2.7725887f));
        const int q = (int)rintf(fminf(p16, 127.f));
        sm8[row * 128 + (((col >> 4) ^ (row & 7)) << 4) + (col & 15)] = (unsigned char)q;
      }
  __syncthreads();
#pragma unroll
  for (int t = 0; t < 4; ++t) {
    const int cid = t * 256 + tid;
    const int row = cid >> 3, blk = cid & 7;
    const unsigned char* hsm = (t < 2) ? As0 : As1;
    const i32x4 v = *(const i32x4*)(hsm + (row & 63) * 128 + ((blk ^ (row & 7)) << 4));
    *(i32x4*)(P8 + (size_t)(tm * 128 + row) * 8192 + tn * 128 + blk * 16) = v;
  }
}

// ---------------- ctx: ctx bf16 = (P8 @ V8^T) / (32 * sum(P8 row)), K=8192 (64 stages) ----------------
__global__ __launch_bounds__(256) void ctx8_kernel(
    const unsigned char* __restrict__ P8, const unsigned char* __restrict__ V8,
    unsigned short* __restrict__ ctx) {
  __shared__ alignas(16) unsigned char As0[16384], As1[16384], Bs0[16384], Bs1[16384];  // 64KB
  const int bx0 = blockIdx.x;
  // XCD-chunked swizzle (512 % 8 == 0, bijective): 8 tn-blocks of a tm share one XCD L2
  const int bx = (bx0 & 7) * 64 + (bx0 >> 3);
  const int tm = bx >> 3, tn = bx & 7;
  i32x16 acc[2][2], accs[2];
  gemm_i8_32<true, 128, false>(P8 + (size_t)(tm * 128) * 8192, 8192,
                               V8 + (size_t)(tn * 128) * 8192, 8192, 64, As0, As1, Bs0, Bs1, acc,
                               accs);
  const int tid = threadIdx.x, w = tid >> 6, l = tid & 63, l31 = l & 31, half = l >> 5;
  const int cl0 = 64 * (w & 1);
  // 128x128 bf16 tile: rows 0..63 in As0, 64..127 in As1 (16KB each)
  unsigned short* sm16 = (unsigned short*)((w < 2) ? As0 : As1);
  const float cs = 1.0f / 32.0f;  // 1/v-scale; p-scale cancels against accs
#pragma unroll
  for (int tr = 0; tr < 2; ++tr)
#pragma unroll
    for (int r = 0; r < 16; ++r) {
      const int lrow = 32 * tr + (r & 3) + 8 * (r >> 2) + 4 * half;  // local 0..63
      const float inv = cs / (float)accs[tr][r];  // exact sum of quantized P row
#pragma unroll
      for (int tc = 0; tc < 2; ++tc) {
        const int col = cl0 + 32 * tc + l31;
        sm16[lrow * 128 + (((col >> 3) ^ (lrow & 15)) << 3) + (col & 7)] =
            f2bf((float)acc[tr][tc][r] * inv);
      }
    }
  __syncthreads();
#pragma unroll
  for (int t2 = 0; t2 < 8; ++t2) {
    const int cid = t2 * 256 + tid;
    const int row = cid >> 4, blk = cid & 15;
    const unsigned short* hsm = (const unsigned short*)((row & 64) ? As1 : As0);
    const bf16x8 v = *(const bf16x8*)(hsm + (row & 63) * 128 + ((blk ^ (row & 15)) << 3));
    *(bf16x8*)(ctx + (size_t)(tm * 128 + row) * 1024 + tn * 128 + blk * 8) = v;
  }
}

// ---------------- output projection: out = ctx @ w_out^T + b_out (fp32 out) ----------------
__global__ __launch_bounds__(256) void proj_kernel(
    const unsigned short* __restrict__ ctxb, const unsigned short* __restrict__ wb,
    const float* __restrict__ bias, float* __restrict__ out) {
  __shared__ alignas(16) unsigned short As0[8192], As1[8192], Bs0[8192], Bs1[8192];  // 64KB
  const int bx0 = blockIdx.x;
  const int bx = (bx0 & 7) * 64 + (bx0 >> 3);
  const int tn = bx & 7, tm = bx >> 3;
  f32x4 acc[4][4];
  gemm_tile2<128>(ctxb + (size_t)(tm * 128) * 1024, 1024, wb + (size_t)(tn * 128) * 1024, 1024,
                  16, As0, As1, Bs0, Bs1, acc);
  const int tid = threadIdx.x, w = tid >> 6, l = tid & 63, lane15 = l & 15, quad = l >> 4;
  const int r0 = tm * 128 + 64 * (w >> 1);
  const int c0 = tn * 128 + 64 * (w & 1);
  float bo[4];
#pragma unroll
  for (int bc = 0; bc < 4; ++bc) bo[bc] = bias[c0 + 16 * bc + lane15];
#pragma unroll
  for (int br = 0; br < 4; ++br)
#pragma unroll
    for (int bc = 0; bc < 4; ++bc)
#pragma unroll
      for (int i = 0; i < 4; ++i)
        out[(size_t)(r0 + 16 * br + 4 * quad + i) * 1024 + c0 + 16 * bc + lane15] =
            acc[br][bc][i] + bo[bc];
}

extern "C" void kernel_launch(void* const* d_in, const int* in_sizes, int n_in,
                              void* d_out, int out_size, void* d_ws, size_t ws_size,
                              hipStream_t stream) {
  const float* x = (const float*)d_in[0];
  const float* wqkv = (const float*)d_in[1];
  const float* bqkv = (const float*)d_in[2];
  const float* wout = (const float*)d_in[3];
  const float* bout = (const float*)d_in[4];
  float* out = (float*)d_out;
  char* ws = (char*)d_ws;

  // Workspace (~125 MB): xb 16M | wqkvb 6M | woutb 2M | Q8 8M | K8 8M | V8 8M | (gap) | P8 64M | ctx 16M
  unsigned short* xb = (unsigned short*)(ws);
  unsigned short* wqkvb = (unsigned short*)(ws + 16777216);
  unsigned short* woutb = (unsigned short*)(ws + 23068672);
  unsigned char* Q8 = (unsigned char*)(ws + 25165824);
  unsigned char* K8 = (unsigned char*)(ws + 33554432);
  unsigned char* V8 = (unsigned char*)(ws + 41943040);
  unsigned char* P8 = (unsigned char*)(ws + 50364416);
  unsigned short* ctx = (unsigned short*)(ws + 117473280);

  convert_kernel<<<12288, 256, 0, stream>>>(x, wqkv, wout, xb, wqkvb, woutb);
  qkv_kernel<<<1536, 256, 0, stream>>>(xb, wqkvb, bqkv, Q8, K8, V8);
  score8_kernel<<<4096, 256, 0, stream>>>(Q8, K8, P8);   // P = i8(exp(QK^T/32)*16)
  ctx8_kernel<<<512, 256, 0, stream>>>(P8, V8, ctx);     // ctx = (P V)/(32*rowsum(P))
  proj_kernel<<<512, 256, 0, stream>>>(ctx, woutb, bout, out);
}

// Round 10
// 325.362 us; speedup vs baseline: 1.0683x; 1.0683x over previous
//
#include <hip/hip_runtime.h>

typedef __attribute__((ext_vector_type(4))) float f32x4;
typedef __attribute__((ext_vector_type(4))) int i32x4;
typedef __attribute__((ext_vector_type(8))) __bf16 bf16x8;

__device__ __forceinline__ unsigned short f2bf(float f) {
  union { float f; unsigned u; } v; v.f = f;
  unsigned r = v.u + 0x7fffu + ((v.u >> 16) & 1u);
  return (unsigned short)(r >> 16);
}

__device__ __forceinline__ void gll16(const void* g, void* s) {
  __builtin_amdgcn_global_load_lds((const __attribute__((address_space(1))) unsigned int*)g,
                                   (__attribute__((address_space(3))) unsigned int*)s, 16, 0, 0);
}

__device__ __forceinline__ int quant8(float x, float s) {
  return (int)rintf(fminf(fmaxf(x * s, -127.f), 127.f));
}

#define MFMA(a, b, c) __builtin_amdgcn_mfma_f32_16x16x32_bf16((a), (b), (c), 0, 0, 0)
#define MFMA_I8(a, b, c) __builtin_amdgcn_mfma_i32_16x16x64_i8((a), (b), (c), 0, 0, 0)

// Counted-vmcnt pipeline barriers (T4): wait only for the stage issued one
// iteration ago (N = VMEM ops/thread/stage in flight), never drain mid-loop.
template <int N>
__device__ __forceinline__ void pipe_wait() {
  if constexpr (N == 8) asm volatile("s_waitcnt vmcnt(8)" ::: "memory");
  else if constexpr (N == 4) asm volatile("s_waitcnt vmcnt(4)" ::: "memory");
  else asm volatile("s_waitcnt vmcnt(0)" ::: "memory");
  __builtin_amdgcn_s_barrier();
  __builtin_amdgcn_sched_barrier(0);
}
__device__ __forceinline__ void pipe_post() {
  __builtin_amdgcn_s_barrier();
  __builtin_amdgcn_sched_barrier(0);
}

// Generic LDS block swizzle for RB-byte rows (RB in {64,128}); 16B blocks.
// RB=128 -> full XOR over row&7; RB=64 -> (row>>1)&3, 2-way aliasing (free, m136).
template <int RB>
__device__ __forceinline__ int swz(int row) {
  return ((row * RB) >> 7) & (RB / 16 - 1);
}

// ---------------- fp32 -> bf16 convert (x, w_qkv, w_out) ----------------
__global__ __launch_bounds__(256) void convert_kernel(
    const float* __restrict__ x, const float* __restrict__ wqkv, const float* __restrict__ wout,
    unsigned short* __restrict__ xb, unsigned short* __restrict__ wqkvb,
    unsigned short* __restrict__ woutb) {
  const long i4 = (long)blockIdx.x * 256 + threadIdx.x;
  const float4* src;
  unsigned short* dst;
  long j;
  if (i4 < 2097152) { src = (const float4*)x; j = i4; dst = xb; }
  else if (i4 < 2883584) { src = (const float4*)wqkv; j = i4 - 2097152; dst = wqkvb; }
  else { src = (const float4*)wout; j = i4 - 2883584; dst = woutb; }
  const float4 v = src[j];
  ushort4 r;
  r.x = f2bf(v.x); r.y = f2bf(v.y); r.z = f2bf(v.z); r.w = f2bf(v.w);
  *(ushort4*)(dst + j * 4) = r;
}

// ---- bf16 128x128 GEMM mainloop, depth-2 counted-vmcnt (R2-proven; no setprio) ----
template <int RB>
__device__ __forceinline__ void gemm_tile2(const unsigned short* __restrict__ A, int lda,
                                           const unsigned short* __restrict__ B, int ldb,
                                           int nstages,  // even, >= 4
                                           unsigned short* As0, unsigned short* As1,
                                           unsigned short* Bs0, unsigned short* Bs1,
                                           f32x4 acc[4][4]) {
  constexpr int SLOTS = RB / 16;   // 16B slots per row
  constexpr int RPC = 1024 / RB;   // rows per 1KB chunk
  constexpr int CPW = RB / 32;     // chunks per wave per operand
  constexpr int WAIT = RB / 16;    // loads/thread/stage (A+B)
  const int tid = threadIdx.x;
  const int w = tid >> 6, l = tid & 63, lane15 = l & 15, quad = l >> 4;
#pragma unroll
  for (int br = 0; br < 4; ++br)
#pragma unroll
    for (int bc = 0; bc < 4; ++bc) acc[br][bc] = f32x4{0.f, 0.f, 0.f, 0.f};
  const int ar0 = 64 * (w >> 1), bc0 = 64 * (w & 1);

  auto stage = [&](unsigned short* as, unsigned short* bs, int st) {
    const int kc = st * (RB / 2);
#pragma unroll
    for (int t = 0; t < CPW; ++t) {
      const int ck = w * CPW + t;
      const int row = ck * RPC + l / SLOTS;
      const int x = (l & (SLOTS - 1)) ^ swz<RB>(row);
      gll16(A + (size_t)row * lda + kc + x * 8, as + ck * 512);
      gll16(B + (size_t)row * ldb + kc + x * 8, bs + ck * 512);
    }
  };
  auto comp = [&](const unsigned short* as, const unsigned short* bs) {
#pragma unroll
    for (int kk = 0; kk < RB / 64; ++kk) {
      bf16x8 a[4], b[4];
#pragma unroll
      for (int br = 0; br < 4; ++br) {
        const int row = ar0 + 16 * br + lane15;
        const int blk = (kk * 4 + quad) ^ swz<RB>(row);
        a[br] = *(const bf16x8*)((const char*)as + row * RB + blk * 16);
      }
#pragma unroll
      for (int bc = 0; bc < 4; ++bc) {
        const int row = bc0 + 16 * bc + lane15;
        const int blk = (kk * 4 + quad) ^ swz<RB>(row);
        b[bc] = *(const bf16x8*)((const char*)bs + row * RB + blk * 16);
      }
#pragma unroll
      for (int br = 0; br < 4; ++br)
#pragma unroll
        for (int bc = 0; bc < 4; ++bc)
          acc[br][bc] = MFMA(a[br], b[bc], acc[br][bc]);
    }
  };

  stage(As0, Bs0, 0);
  stage(As1, Bs1, 1);
  for (int st = 0; st < nstages - 2; st += 2) {
    pipe_wait<WAIT>();
    comp(As0, Bs0);
    pipe_post();
    stage(As0, Bs0, st + 2);
    pipe_wait<WAIT>();
    comp(As1, Bs1);
    pipe_post();
    stage(As1, Bs1, st + 3);
  }
  pipe_wait<WAIT>();
  comp(As0, Bs0);
  pipe_wait<0>();
  comp(As1, Bs1);
  __syncthreads();  // epilogues may reuse LDS
}

// ---- i8 128x128 GEMM mainloop, 2-buffer depth-2 counted-vmcnt (R2-proven).
// SUM: exact row-sums of A via ones-column MFMA. PRIO: setprio around MFMA. ----
template <bool SUM, int RB, bool PRIO>
__device__ __forceinline__ void gemm_tile_i8(const unsigned char* __restrict__ A, int lda,
                                             const unsigned char* __restrict__ B, int ldb,
                                             int nstages,  // even, >= 4
                                             unsigned char* As0, unsigned char* As1,
                                             unsigned char* Bs0, unsigned char* Bs1,
                                             i32x4 acc[4][4], i32x4* accs) {
  constexpr int SLOTS = RB / 16;
  constexpr int RPC = 1024 / RB;
  constexpr int CPW = RB / 32;  // chunks per wave per operand
  constexpr int WAIT = RB / 16;
  const int tid = threadIdx.x;
  const int w = tid >> 6, l = tid & 63, lane15 = l & 15, quad = l >> 4;
#pragma unroll
  for (int br = 0; br < 4; ++br)
#pragma unroll
    for (int bc = 0; bc < 4; ++bc) acc[br][bc] = i32x4{0, 0, 0, 0};
  if constexpr (SUM) {
#pragma unroll
    for (int br = 0; br < 4; ++br) accs[br] = i32x4{0, 0, 0, 0};
  }
  const int ar0 = 64 * (w >> 1), bc0 = 64 * (w & 1);

  auto stage = [&](unsigned char* as, unsigned char* bs, int st) {
    const int kc = st * RB;
#pragma unroll
    for (int t = 0; t < CPW; ++t) {
      const int ck = w * CPW + t;
      const int row = ck * RPC + l / SLOTS;
      const int x = (l & (SLOTS - 1)) ^ swz<RB>(row);
      gll16(A + (size_t)row * lda + kc + x * 16, as + ck * 1024);
      gll16(B + (size_t)row * ldb + kc + x * 16, bs + ck * 1024);
    }
  };
  auto comp = [&](const unsigned char* as, const unsigned char* bs) {
#pragma unroll
    for (int kk = 0; kk < RB / 64; ++kk) {
      i32x4 a[4], b[4];
#pragma unroll
      for (int br = 0; br < 4; ++br) {
        const int row = ar0 + 16 * br + lane15;
        const int blk = (kk * 4 + quad) ^ swz<RB>(row);
        a[br] = *(const i32x4*)(as + row * RB + blk * 16);
      }
#pragma unroll
      for (int bc = 0; bc < 4; ++bc) {
        const int row = bc0 + 16 * bc + lane15;
        const int blk = (kk * 4 + quad) ^ swz<RB>(row);
        b[bc] = *(const i32x4*)(bs + row * RB + blk * 16);
      }
      if constexpr (PRIO) __builtin_amdgcn_s_setprio(1);
      if constexpr (SUM) {
        const i32x4 ones = {0x01010101, 0x01010101, 0x01010101, 0x01010101};
#pragma unroll
        for (int br = 0; br < 4; ++br) accs[br] = MFMA_I8(a[br], ones, accs[br]);
      }
#pragma unroll
      for (int br = 0; br < 4; ++br)
#pragma unroll
        for (int bc = 0; bc < 4; ++bc)
          acc[br][bc] = MFMA_I8(a[br], b[bc], acc[br][bc]);
      if constexpr (PRIO) __builtin_amdgcn_s_setprio(0);
    }
  };

  stage(As0, Bs0, 0);
  stage(As1, Bs1, 1);
  for (int st = 0; st < nstages - 2; st += 2) {
    pipe_wait<WAIT>();
    comp(As0, Bs0);
    pipe_post();
    stage(As0, Bs0, st + 2);
    pipe_wait<WAIT>();
    comp(As1, Bs1);
    pipe_post();
    stage(As1, Bs1, st + 3);
  }
  pipe_wait<WAIT>();
  comp(As0, Bs0);
  pipe_wait<0>();
  comp(As1, Bs1);
  __syncthreads();  // epilogues may reuse LDS
}

// sigma permutation: original k-offset o (within a 64-group) stored at
// sigma(o) = 4*(o&15) + (o>>4). Applied to BOTH P8 columns and V8 s-columns,
// so ctx8's k-dot-products (and ones-rowsums) are invariant.

// ---------------- QKV projection (bf16 GEMM) -> Q8/K8 [8192][1024] i8 (x32), V8^T [1024][8192] i8 (x32, sigma-permuted s) ----------------
__global__ __launch_bounds__(256) void qkv_kernel(
    const unsigned short* __restrict__ xb, const unsigned short* __restrict__ wb,
    const float* __restrict__ bias, unsigned char* __restrict__ Q8,
    unsigned char* __restrict__ K8, unsigned char* __restrict__ V8) {
  __shared__ alignas(16) unsigned short As0[8192], As1[8192], Bs0[8192], Bs1[8192];  // 64KB
  const int bx0 = blockIdx.x;
  // XCD-chunked swizzle (1536 % 8 == 0, bijective)
  const int bx = (bx0 & 7) * 192 + (bx0 >> 3);
  const int tn = bx % 24, tm = bx / 24;
  f32x4 acc[4][4];
  gemm_tile2<128>(xb + (size_t)(tm * 128) * 1024, 1024, wb + (size_t)(tn * 128) * 1024, 1024, 16,
                  As0, As1, Bs0, Bs1, acc);
  const int tid = threadIdx.x, w = tid >> 6, l = tid & 63, lane15 = l & 15, quad = l >> 4;
  const int rl0 = 64 * (w >> 1), cl0 = 64 * (w & 1);
  float bq[4];
#pragma unroll
  for (int bc = 0; bc < 4; ++bc) bq[bc] = bias[tn * 128 + cl0 + 16 * bc + lane15];
  if (tn < 16) {  // Q or K tile: quantize to i8, LDS transpose, coalesced 16B stores
    unsigned char* sm8 = (unsigned char*)As0;  // 16KB: full 128x128 i8 tile
#pragma unroll
    for (int br = 0; br < 4; ++br)
#pragma unroll
      for (int bc = 0; bc < 4; ++bc)
#pragma unroll
        for (int i = 0; i < 4; ++i) {
          const int row = rl0 + 16 * br + 4 * quad + i;
          const int col = cl0 + 16 * bc + lane15;
          const int q = quant8(acc[br][bc][i] + bq[bc], 32.f);
          sm8[row * 128 + (((col >> 4) ^ (row & 7)) << 4) + (col & 15)] = (unsigned char)q;
        }
    __syncthreads();
    unsigned char* dst = (tn < 8) ? Q8 : K8;
    const int ccol = (tn < 8) ? tn * 128 : (tn - 8) * 128;
#pragma unroll
    for (int t = 0; t < 4; ++t) {
      const int cid = t * 256 + tid;
      const int row = cid >> 3, blk = cid & 7;
      const i32x4 v = *(const i32x4*)(sm8 + row * 128 + ((blk ^ (row & 7)) << 4));
      *(i32x4*)(dst + (size_t)(tm * 128 + row) * 1024 + ccol + blk * 16) = v;
    }
  } else {  // V tile -> V8[d][sigma(s)]: 16 bytes per (bc) pack into one 16B store
#pragma unroll
    for (int bc = 0; bc < 4; ++bc) {
      const int d = (tn - 16) * 128 + cl0 + 16 * bc + lane15;
      i32x4 dv;
#pragma unroll
      for (int i = 0; i < 4; ++i) {
        unsigned dw = 0;
#pragma unroll
        for (int br = 0; br < 4; ++br) {
          const int q = quant8(acc[br][bc][i] + bq[bc], 32.f);
          dw |= (unsigned)(q & 255) << (8 * br);
        }
        dv[i] = (int)dw;
      }
      // positions sigma(16*br + 4*quad + i) = 16*quad + 4*i + br within the 64-group
      *(i32x4*)(V8 + (size_t)d * 8192 + tm * 128 + rl0 + 16 * quad) = dv;
    }
  }
}

// ---------------- score: P8[8192][sigma-permuted 8192] = i8(exp(QK^T/32) * 16) ----------------
// R5-measured config (92 us): 2-buf RB=64 counted-vmcnt, setprio, sigma ->
// direct 64B-coalesced dword stores (no LDS transpose), exp-fold epilogue.
__global__ __launch_bounds__(256) void score8_kernel(
    const unsigned char* __restrict__ Q8, const unsigned char* __restrict__ K8,
    unsigned char* __restrict__ P8) {
  __shared__ alignas(16) unsigned char As0[8192], As1[8192], Bs0[8192], Bs1[8192];  // 32KB
  const int tm = blockIdx.x >> 6, tn = blockIdx.x & 63;
  i32x4 acc[4][4];
  gemm_tile_i8<false, 64, true>(Q8 + (size_t)(tm * 128) * 1024, 1024,
                                K8 + (size_t)(tn * 128) * 1024, 1024, 16, As0, As1, Bs0, Bs1,
                                acc, (i32x4*)nullptr);
  const int tid = threadIdx.x, w = tid >> 6, l = tid & 63, lane15 = l & 15, quad = l >> 4;
  const int rl0 = 64 * (w >> 1), cl0 = 64 * (w & 1);
  const float csc = 1.0f / 32768.0f;  // 1/(32*32) quant scales * 1/32 softmax scale
  const size_t colbase = (size_t)tn * 128 + cl0 + 4 * lane15;
#pragma unroll
  for (int br = 0; br < 4; ++br)
#pragma unroll
    for (int i = 0; i < 4; ++i) {
      const int row = rl0 + 16 * br + 4 * quad + i;
      unsigned dw = 0;
#pragma unroll
      for (int bc = 0; bc < 4; ++bc) {
        // p*16 = exp(x)*16 = exp(x + ln16): fold the *16 into the exp argument
        const float p16 = __expf(fmaf((float)acc[br][bc][i], csc, 2.7725887f));
        const int q = (int)rintf(fminf(p16, 127.f));
        dw |= (unsigned)(q & 255) << (8 * bc);
      }
      *(unsigned*)(P8 + (size_t)(tm * 128 + row) * 8192 + colbase) = dw;
    }
}

// ---------------- ctx: ctx bf16 = (P8 @ V8^T) / (32 * sum(P8 row)), K=8192 (64 stages) ----------------
__global__ __launch_bounds__(256) void ctx8_kernel(
    const unsigned char* __restrict__ P8, const unsigned char* __restrict__ V8,
    unsigned short* __restrict__ ctx) {
  __shared__ alignas(16) unsigned char As0[16384], As1[16384], Bs0[16384], Bs1[16384];  // 64KB
  const int bx0 = blockIdx.x;
  // XCD-chunked swizzle (512 % 8 == 0, bijective): 8 tn-blocks of a tm share one XCD L2
  const int bx = (bx0 & 7) * 64 + (bx0 >> 3);
  const int tm = bx >> 3, tn = bx & 7;
  i32x4 acc[4][4], accs[4];
  gemm_tile_i8<true, 128, false>(P8 + (size_t)(tm * 128) * 8192, 8192,
                                 V8 + (size_t)(tn * 128) * 8192, 8192, 64, As0, As1, Bs0, Bs1,
                                 acc, accs);
  const int tid = threadIdx.x, w = tid >> 6, l = tid & 63, lane15 = l & 15, quad = l >> 4;
  const int rl0 = 64 * (w >> 1), cl0 = 64 * (w & 1);
  // 128x128 bf16 tile: rows 0..63 in As0, 64..127 in As1 (16KB each)
  unsigned short* sm16 = (unsigned short*)((w < 2) ? As0 : As1);
  const float cs = 1.0f / 32.0f;  // 1/v-scale; p-scale cancels against accs
#pragma unroll
  for (int br = 0; br < 4; ++br)
#pragma unroll
    for (int i = 0; i < 4; ++i) {
      const int row = rl0 + 16 * br + 4 * quad + i;
      const float inv = cs / (float)accs[br][i];  // exact sum of quantized P row
#pragma unroll
      for (int bc = 0; bc < 4; ++bc) {
        const int col = cl0 + 16 * bc + lane15;
        sm16[(row & 63) * 128 + (((col >> 3) ^ (row & 15)) << 3) + (col & 7)] =
            f2bf((float)acc[br][bc][i] * inv);
      }
    }
  __syncthreads();
#pragma unroll
  for (int t2 = 0; t2 < 8; ++t2) {
    const int cid = t2 * 256 + tid;
    const int row = cid >> 4, blk = cid & 15;
    const unsigned short* half = (const unsigned short*)((row & 64) ? As1 : As0);
    const bf16x8 v = *(const bf16x8*)(half + (row & 63) * 128 + ((blk ^ (row & 15)) << 3));
    *(bf16x8*)(ctx + (size_t)(tm * 128 + row) * 1024 + tn * 128 + blk * 8) = v;
  }
}

// ---------------- output projection: out = ctx @ w_out^T + b_out (fp32 out) ----------------
__global__ __launch_bounds__(256) void proj_kernel(
    const unsigned short* __restrict__ ctxb, const unsigned short* __restrict__ wb,
    const float* __restrict__ bias, float* __restrict__ out) {
  __shared__ alignas(16) unsigned short As0[8192], As1[8192], Bs0[8192], Bs1[8192];  // 64KB
  const int bx0 = blockIdx.x;
  const int bx = (bx0 & 7) * 64 + (bx0 >> 3);
  const int tn = bx & 7, tm = bx >> 3;
  f32x4 acc[4][4];
  gemm_tile2<128>(ctxb + (size_t)(tm * 128) * 1024, 1024, wb + (size_t)(tn * 128) * 1024, 1024,
                  16, As0, As1, Bs0, Bs1, acc);
  const int tid = threadIdx.x, w = tid >> 6, l = tid & 63, lane15 = l & 15, quad = l >> 4;
  const int r0 = tm * 128 + 64 * (w >> 1);
  const int c0 = tn * 128 + 64 * (w & 1);
  float bo[4];
#pragma unroll
  for (int bc = 0; bc < 4; ++bc) bo[bc] = bias[c0 + 16 * bc + lane15];
#pragma unroll
  for (int br = 0; br < 4; ++br)
#pragma unroll
    for (int bc = 0; bc < 4; ++bc)
#pragma unroll
      for (int i = 0; i < 4; ++i)
        out[(size_t)(r0 + 16 * br + 4 * quad + i) * 1024 + c0 + 16 * bc + lane15] =
            acc[br][bc][i] + bo[bc];
}

extern "C" void kernel_launch(void* const* d_in, const int* in_sizes, int n_in,
                              void* d_out, int out_size, void* d_ws, size_t ws_size,
                              hipStream_t stream) {
  const float* x = (const float*)d_in[0];
  const float* wqkv = (const float*)d_in[1];
  const float* bqkv = (const float*)d_in[2];
  const float* wout = (const float*)d_in[3];
  const float* bout = (const float*)d_in[4];
  float* out = (float*)d_out;
  char* ws = (char*)d_ws;

  // Workspace (~125 MB): xb 16M | wqkvb 6M | woutb 2M | Q8 8M | K8 8M | V8 8M | (gap) | P8 64M | ctx 16M
  unsigned short* xb = (unsigned short*)(ws);
  unsigned short* wqkvb = (unsigned short*)(ws + 16777216);
  unsigned short* woutb = (unsigned short*)(ws + 23068672);
  unsigned char* Q8 = (unsigned char*)(ws + 25165824);
  unsigned char* K8 = (unsigned char*)(ws + 33554432);
  unsigned char* V8 = (unsigned char*)(ws + 41943040);
  unsigned char* P8 = (unsigned char*)(ws + 50364416);
  unsigned short* ctx = (unsigned short*)(ws + 117473280);

  convert_kernel<<<12288, 256, 0, stream>>>(x, wqkv, wout, xb, wqkvb, woutb);
  qkv_kernel<<<1536, 256, 0, stream>>>(xb, wqkvb, bqkv, Q8, K8, V8);
  score8_kernel<<<4096, 256, 0, stream>>>(Q8, K8, P8);   // P = i8(exp(QK^T/32)*16), sigma cols
  ctx8_kernel<<<512, 256, 0, stream>>>(P8, V8, ctx);     // ctx = (P V)/(32*rowsum(P))
  proj_kernel<<<512, 256, 0, stream>>>(ctx, woutb, bout, out);
}